// Round 9
// baseline (106.540 us; speedup 1.0000x reference)
//
#include <hip/hip_runtime.h>
#include <math.h>

// Problem constants (match reference)
constexpr int B_ = 32;
constexpr int C_ = 32;
constexpr int RES_ = 16;
constexpr int G_ = RES_ * RES_ * RES_;   // 4096
constexpr int N_ = 16384;
constexpr int H_ = 64;
// sqrt(3)/RES
__device__ constexpr float REG_THR = 0.10825317547305483f;

typedef __attribute__((ext_vector_type(2))) float v2f;

__device__ __forceinline__ v2f fma2(v2f a, v2f b, v2f c) {
    return __builtin_elementwise_fma(a, b, c);
}

// float -> bf16 bits, round-to-nearest-even (values are finite here).
__device__ __forceinline__ unsigned short f2bf(float f) {
    union { float f; unsigned int u; } v; v.f = f;
    const unsigned int r = v.u + 0x7FFFu + ((v.u >> 16) & 1u);
    return (unsigned short)(r >> 16);
}

// ---------------------------------------------------------------------------
// Kernel A (fused): hx compute + per-batch scan/scatter.
//
// R17: hx was LDS-ISSUE-bound: 4096 ds_read_b64/CU x ~8cyc ~= 13.6 us
// (matches measured share; pk-FMA VALU is only ~1.7 us in parallel).
// Fix = more FMA per weight broadcast:
//   - TCELL 256, FOUR cells/thread (halves LDS instrs per FMA)
//   - b128 weight loads (2 channel-pairs per read; halves instr count again)
// New LDS cost/CU ~= 1024 b128 x 12cyc ~= 5 us. LDS 43 KB -> 3 blocks/CU
// (issue-bound; 12 waves/CU suffice). VGPR ~170 (xv=128) — below spill line,
// NO __launch_bounds__ min-waves floor (R13's 337 MB scratch lesson).
// ---------------------------------------------------------------------------
constexpr int TCELL = 256;    // cells per block (4 per thread)
constexpr int RS = 33;        // s_hx row stride in uints (odd: bank-safe)
constexpr int WROW = 36;      // W1 LDS row stride (floats; 144 B: b128-aligned)

__global__ __launch_bounds__(256) void hx_scan_kernel(
    const float* __restrict__ x, const float* __restrict__ W1,
    const float* __restrict__ b1, const int* __restrict__ counts,
    unsigned short* __restrict__ hxb, int* __restrict__ idxarr) {
    const int b = blockIdx.y;
    const int t = threadIdx.x;

    __shared__ float __align__(16) s_w1[H_ * WROW];   // 9.2 KB
    __shared__ unsigned int s_hx[TCELL * RS];         // 33.8 KB

    if (blockIdx.x == G_ / TCELL) {
        // ---- scan + scatter (one block per batch) ----
        int* partials = (int*)s_w1;                   // 1 KB alias
        const int* cb = counts + b * G_;
        const int base = t * 16;
        int local[16];
        int s = 0;
#pragma unroll
        for (int i = 0; i < 16; ++i) { s += cb[base + i]; local[i] = s; }
        partials[t] = s;
        __syncthreads();
        for (int off = 1; off < 256; off <<= 1) {
            int v = (t >= off) ? partials[t - off] : 0;
            __syncthreads();
            partials[t] += v;
            __syncthreads();
        }
        const int prev = (t > 0) ? partials[t - 1] : 0;

        int* ib = idxarr + b * N_;
        int startk = prev;
#pragma unroll
        for (int i = 0; i < 16; ++i) {
            const int endk = prev + local[i];
            const int cell = base + i;
            const int k0 = startk > 0 ? startk : 0;        // poison-safe
            const int k1 = endk < N_ ? endk : N_;
            for (int k = k0; k < k1; ++k) ib[k] = cell;
            startk = endk;
        }
        return;
    }

    // ---- hx branch ----
    const int tile = blockIdx.x * TCELL;
    const int cell_l = t & 63;                 // lane = cell (within quarter)
    const int hh2 = __builtin_amdgcn_readfirstlane((t >> 6) * 8); // uint idx

    // Cooperative W1 fill (2176 floats) + b1 into the row pad.
    for (int i = t; i < H_ * 34; i += 256) {
        const int r = i / 34;
        const int c = i - r * 34;
        s_w1[r * WROW + c] = W1[i];
    }
    if (t < H_) s_w1[t * WROW + 34] = b1[t];

    // Coalesced x loads for FOUR cells, packed as channel pairs.
    const float* xb = x + ((size_t)b * C_) * G_ + tile + cell_l;
    v2f xv0[C_ / 2], xv1[C_ / 2], xv2[C_ / 2], xv3[C_ / 2];
#pragma unroll
    for (int c2 = 0; c2 < C_ / 2; ++c2) {
        const size_t o0 = (size_t)(2 * c2 + 0) * G_;
        const size_t o1 = (size_t)(2 * c2 + 1) * G_;
        xv0[c2].x = xb[o0];       xv0[c2].y = xb[o1];
        xv1[c2].x = xb[o0 + 64];  xv1[c2].y = xb[o1 + 64];
        xv2[c2].x = xb[o0 + 128]; xv2[c2].y = xb[o1 + 128];
        xv3[c2].x = xb[o0 + 192]; xv3[c2].y = xb[o1 + 192];
    }
    __syncthreads();

    // 8 h-pairs per thread x 4 cells; b128 weight broadcasts (2 ch-pairs).
    unsigned int* row0 = s_hx + (cell_l +   0) * RS + hh2;
    unsigned int* row1 = s_hx + (cell_l +  64) * RS + hh2;
    unsigned int* row2 = s_hx + (cell_l + 128) * RS + hh2;
    unsigned int* row3 = s_hx + (cell_l + 192) * RS + hh2;
#pragma unroll 2
    for (int j = 0; j < 8; ++j) {
        const float* we = s_w1 + (2 * (hh2 + j) + 0) * WROW;
        const float* wo = s_w1 + (2 * (hh2 + j) + 1) * WROW;
        v2f e0p = {0.f, 0.f}, q0p = {0.f, 0.f};
        v2f e1p = {0.f, 0.f}, q1p = {0.f, 0.f};
        v2f e2p = {0.f, 0.f}, q2p = {0.f, 0.f};
        v2f e3p = {0.f, 0.f}, q3p = {0.f, 0.f};
#pragma unroll
        for (int c4 = 0; c4 < C_ / 4; ++c4) {
            const float4 we4 = *(const float4*)(we + 4 * c4); // b128 bcast
            const float4 wo4 = *(const float4*)(wo + 4 * c4);
            v2f wea; wea.x = we4.x; wea.y = we4.y;
            v2f web; web.x = we4.z; web.y = we4.w;
            v2f woa; woa.x = wo4.x; woa.y = wo4.y;
            v2f wob; wob.x = wo4.z; wob.y = wo4.w;
            const int ca = 2 * c4, cb2 = 2 * c4 + 1;
            e0p = fma2(wea, xv0[ca], e0p); e0p = fma2(web, xv0[cb2], e0p);
            q0p = fma2(woa, xv0[ca], q0p); q0p = fma2(wob, xv0[cb2], q0p);
            e1p = fma2(wea, xv1[ca], e1p); e1p = fma2(web, xv1[cb2], e1p);
            q1p = fma2(woa, xv1[ca], q1p); q1p = fma2(wob, xv1[cb2], q1p);
            e2p = fma2(wea, xv2[ca], e2p); e2p = fma2(web, xv2[cb2], e2p);
            q2p = fma2(woa, xv2[ca], q2p); q2p = fma2(wob, xv2[cb2], q2p);
            e3p = fma2(wea, xv3[ca], e3p); e3p = fma2(web, xv3[cb2], e3p);
            q3p = fma2(woa, xv3[ca], q3p); q3p = fma2(wob, xv3[cb2], q3p);
        }
        const float be = we[34], bo = wo[34];             // b1[h]
        const float e0 = be + e0p.x + e0p.y, q0 = bo + q0p.x + q0p.y;
        const float e1 = be + e1p.x + e1p.y, q1 = bo + q1p.x + q1p.y;
        const float e2 = be + e2p.x + e2p.y, q2 = bo + q2p.x + q2p.y;
        const float e3 = be + e3p.x + e3p.y, q3 = bo + q3p.x + q3p.y;
        // bank = (cell + const)%32 across lanes: 2 lanes/bank = free
        row0[j] = (unsigned int)f2bf(e0) | ((unsigned int)f2bf(q0) << 16);
        row1[j] = (unsigned int)f2bf(e1) | ((unsigned int)f2bf(q1) << 16);
        row2[j] = (unsigned int)f2bf(e2) | ((unsigned int)f2bf(q2) << 16);
        row3[j] = (unsigned int)f2bf(e3) | ((unsigned int)f2bf(q3) << 16);
    }
    __syncthreads();

    // Copy-out: already bf16-packed; linear coalesced uint4 stores.
    uint4* ob4 = (uint4*)(hxb + ((size_t)b * G_ + tile) * H_);
#pragma unroll
    for (int k = 0; k < 8; ++k) {
        const int L4 = t + k * 256;            // uint4 index (8 bf16)
        const int cell = L4 >> 3;
        const int base = (L4 & 7) * 4;         // uint offset within cell
        const unsigned int* s = s_hx + cell * RS + base;
        ob4[L4] = make_uint4(s[0], s[1], s[2], s[3]);
    }
}

// ---------------------------------------------------------------------------
// Kernel B: one thread per (b, n) point.  (unchanged from R16)
//   idx = idxarr[b][n] & (G-1)   (poison-safe, 1 op)
//   Layer 1 scalar fmaf; ReLU + layer 2 packed (v_pk_max/v_pk_fma).
//   W1/W2/b2 stay uniform-address global loads (R9: don't use LDS pipe).
// ---------------------------------------------------------------------------
__global__ __launch_bounds__(256) void point_kernel(
    const unsigned short* __restrict__ hxb, const float* __restrict__ b_rnd,
    const float* __restrict__ W1, const float* __restrict__ W2,
    const float* __restrict__ b2, const int* __restrict__ idxarr,
    float* __restrict__ out0, float* __restrict__ reg_out) {
    const int b = blockIdx.y;
    const int n = blockIdx.x * 256 + threadIdx.x;

    const int idx = idxarr[(size_t)b * N_ + n] & (G_ - 1);   // poison-safe
    const float r0 = b_rnd[((size_t)b * 2 + 0) * N_ + n];
    const float r1 = b_rnd[((size_t)b * 2 + 1) * N_ + n];
    const unsigned short* hp = hxb + ((size_t)b * G_ + idx) * H_;

    v2f o0p = {0.f, 0.f}, o1p = {0.f, 0.f}, o2p = {0.f, 0.f};
    const v2f zz = {0.f, 0.f};
#pragma unroll
    for (int g = 0; g < 8; ++g) {              // 8 h per group, one uint4
        const uint4 u = *(const uint4*)(hp + g * 8);
        const unsigned int uw[4] = {u.x, u.y, u.z, u.w};
#pragma unroll
        for (int q = 0; q < 4; ++q) {
            const int h = g * 8 + 2 * q;       // even h of the pair
            union { unsigned int u; float f; } a, bwd;
            a.u = uw[q] << 16;                 // even h
            bwd.u = uw[q] & 0xFFFF0000u;       // odd h
            // Layer 1: scalar (non-contiguous W1 pairs)
            float he = a.f, ho = bwd.f;
            he = fmaf(W1[h * 34 + 32], r0, he);
            he = fmaf(W1[h * 34 + 33], r1, he);
            ho = fmaf(W1[(h + 1) * 34 + 32], r0, ho);
            ho = fmaf(W1[(h + 1) * 34 + 33], r1, ho);
            // ReLU + layer 2: packed
            v2f hv2; hv2.x = he; hv2.y = ho;
            hv2 = __builtin_elementwise_max(hv2, zz);
            o0p = fma2(*(const v2f*)(W2 + 0 * H_ + h), hv2, o0p);
            o1p = fma2(*(const v2f*)(W2 + 1 * H_ + h), hv2, o1p);
            o2p = fma2(*(const v2f*)(W2 + 2 * H_ + h), hv2, o2p);
        }
    }
    float o0 = b2[0] + o0p.x + o0p.y;
    float o1 = b2[1] + o1p.x + o1p.y;
    float o2 = b2[2] + o2p.x + o2p.y;

    const float nrm = sqrtf(o0 * o0 + o1 * o1 + o2 * o2);
    const float reg = fmaxf(nrm - REG_THR, 0.0f);

    // grid_o[k][idx] = (i_k + 0.5)/16 - 0.5, exact in fp32 from idx bits.
    o0 += (float)((idx >> 8) & 15) * 0.0625f - 0.46875f;
    o1 += (float)((idx >> 4) & 15) * 0.0625f - 0.46875f;
    o2 += (float)(idx & 15) * 0.0625f - 0.46875f;

    float* p = out0 + ((size_t)b * 3) * N_ + n;
    p[0]              = o0;
    p[N_]             = o1;
    p[2 * (size_t)N_] = o2;
    reg_out[(size_t)b * N_ + n] = reg;
}

// ---------------------------------------------------------------------------
extern "C" void kernel_launch(void* const* d_in, const int* in_sizes, int n_in,
                              void* d_out, int out_size, void* d_ws, size_t ws_size,
                              hipStream_t stream) {
    const float* x      = (const float*)d_in[0];  // (B, C, RES, RES, RES)
    const int*   counts = (const int*)  d_in[1];  // (B, G)
    const float* b_rnd  = (const float*)d_in[2];  // (B, 2, N)
    // d_in[3] = grid_o: unused (recomputed exactly from idx bits)
    const float* W1     = (const float*)d_in[4];  // (H, C+2)
    const float* b1     = (const float*)d_in[5];  // (H,)
    const float* W2     = (const float*)d_in[6];  // (3, H)
    const float* b2     = (const float*)d_in[7];  // (3,)

    float* out  = (float*)d_out;                  // (B, 3, N) then (B, N)
    float* rout = out + (size_t)B_ * 3 * N_;

    int* idxarr = (int*)d_ws;                     // B*N ints = 2 MB
    unsigned short* hxb =
        (unsigned short*)((char*)d_ws + (size_t)B_ * N_ * sizeof(int));
                                                  // B*G*H bf16 = 16.8 MB

    dim3 gridA(G_ / TCELL + 1, B_);               // (17, 32): +1 col = scan
    dim3 gridB(N_ / 256, B_);

    hx_scan_kernel<<<gridA, 256, 0, stream>>>(x, W1, b1, counts, hxb, idxarr);
    point_kernel<<<gridB, 256, 0, stream>>>(hxb, b_rnd, W1, W2, b2,
                                            idxarr, out, rout);
}

// Round 10
// 103.062 us; speedup vs baseline: 1.0337x; 1.0337x over previous
//
#include <hip/hip_runtime.h>
#include <math.h>

// Problem constants (match reference)
constexpr int B_ = 32;
constexpr int C_ = 32;
constexpr int RES_ = 16;
constexpr int G_ = RES_ * RES_ * RES_;   // 4096
constexpr int N_ = 16384;
constexpr int H_ = 64;
// sqrt(3)/RES
__device__ constexpr float REG_THR = 0.10825317547305483f;

typedef __attribute__((ext_vector_type(2))) float v2f;

__device__ __forceinline__ v2f fma2(v2f a, v2f b, v2f c) {
    return __builtin_elementwise_fma(a, b, c);
}

// float -> bf16 bits, round-to-nearest-even (values are finite here).
__device__ __forceinline__ unsigned short f2bf(float f) {
    union { float f; unsigned int u; } v; v.f = f;
    const unsigned int r = v.u + 0x7FFFu + ((v.u >> 16) & 1u);
    return (unsigned short)(r >> 16);
}

// ---------------------------------------------------------------------------
// Kernel A (fused): hx compute + per-batch scan/scatter.
//
// R18 = R16's proven 104.7-us structure (TCELL=128, 1056 blocks, 26.6 KB
// LDS, 2 cells/thread) with ONE isolated delta: b128 weight broadcasts
// (float4 = 2 channel-pairs per LDS read, 128 instr/wave vs 256). R17
// bundled this with TCELL=256 (544-block grid, 43 KB LDS, 128-float
// x-footprint) and measured +1.8 us — the bundle confounded the test; this
// round decomposes it. FMA order identical to R16 -> bit-identical output.
// ---------------------------------------------------------------------------
constexpr int TCELL = 128;    // cells per block (2 per thread)
constexpr int RS = 33;        // s_hx row stride in uints (odd: bank-safe)
constexpr int WROW = 36;      // W1 LDS row stride (floats; 144 B: b128-aligned)

__global__ __launch_bounds__(256) void hx_scan_kernel(
    const float* __restrict__ x, const float* __restrict__ W1,
    const float* __restrict__ b1, const int* __restrict__ counts,
    unsigned short* __restrict__ hxb, int* __restrict__ idxarr) {
    const int b = blockIdx.y;
    const int t = threadIdx.x;

    __shared__ float __align__(16) s_w1[H_ * WROW];   // 9.2 KB
    __shared__ unsigned int s_hx[TCELL * RS];         // 16.9 KB

    if (blockIdx.x == G_ / TCELL) {
        // ---- scan + scatter (one block per batch) ----
        int* partials = (int*)s_w1;                   // 1 KB alias
        const int* cb = counts + b * G_;
        const int base = t * 16;
        int local[16];
        int s = 0;
#pragma unroll
        for (int i = 0; i < 16; ++i) { s += cb[base + i]; local[i] = s; }
        partials[t] = s;
        __syncthreads();
        for (int off = 1; off < 256; off <<= 1) {
            int v = (t >= off) ? partials[t - off] : 0;
            __syncthreads();
            partials[t] += v;
            __syncthreads();
        }
        const int prev = (t > 0) ? partials[t - 1] : 0;

        int* ib = idxarr + b * N_;
        int startk = prev;
#pragma unroll
        for (int i = 0; i < 16; ++i) {
            const int endk = prev + local[i];
            const int cell = base + i;
            const int k0 = startk > 0 ? startk : 0;        // poison-safe
            const int k1 = endk < N_ ? endk : N_;
            for (int k = k0; k < k1; ++k) ib[k] = cell;
            startk = endk;
        }
        return;
    }

    // ---- hx branch ----
    const int tile = blockIdx.x * TCELL;
    const int cell_l = t & 63;                 // lane = cell (within half-tile)
    const int hh2 = __builtin_amdgcn_readfirstlane((t >> 6) * 8); // uint idx

    // Cooperative W1 fill (2176 floats) + b1 into the row pad.
    for (int i = t; i < H_ * 34; i += 256) {
        const int r = i / 34;
        const int c = i - r * 34;
        s_w1[r * WROW + c] = W1[i];
    }
    if (t < H_) s_w1[t * WROW + 34] = b1[t];

    // Coalesced x loads for BOTH cells, packed as channel pairs.
    const float* xb = x + ((size_t)b * C_) * G_ + tile + cell_l;
    v2f xv0[C_ / 2], xv1[C_ / 2];
#pragma unroll
    for (int c2 = 0; c2 < C_ / 2; ++c2) {
        const size_t o0 = (size_t)(2 * c2 + 0) * G_;
        const size_t o1 = (size_t)(2 * c2 + 1) * G_;
        xv0[c2].x = xb[o0];       xv0[c2].y = xb[o1];
        xv1[c2].x = xb[o0 + 64];  xv1[c2].y = xb[o1 + 64];
    }
    __syncthreads();

    // 8 h-pairs per thread x 2 cells; b128 weight broadcasts (2 ch-pairs).
    unsigned int* row0 = s_hx + cell_l * RS + hh2;
    unsigned int* row1 = s_hx + (cell_l + 64) * RS + hh2;
#pragma unroll 2
    for (int j = 0; j < 8; ++j) {
        const float* we = s_w1 + (2 * (hh2 + j) + 0) * WROW;
        const float* wo = s_w1 + (2 * (hh2 + j) + 1) * WROW;
        v2f e0p = {0.f, 0.f}, q0p = {0.f, 0.f};
        v2f e1p = {0.f, 0.f}, q1p = {0.f, 0.f};
#pragma unroll
        for (int c4 = 0; c4 < C_ / 4; ++c4) {
            const float4 we4 = *(const float4*)(we + 4 * c4); // b128 bcast
            const float4 wo4 = *(const float4*)(wo + 4 * c4);
            v2f wea; wea.x = we4.x; wea.y = we4.y;
            v2f web; web.x = we4.z; web.y = we4.w;
            v2f woa; woa.x = wo4.x; woa.y = wo4.y;
            v2f wob; wob.x = wo4.z; wob.y = wo4.w;
            const int ca = 2 * c4, cb2 = 2 * c4 + 1;
            e0p = fma2(wea, xv0[ca], e0p); e0p = fma2(web, xv0[cb2], e0p);
            q0p = fma2(woa, xv0[ca], q0p); q0p = fma2(wob, xv0[cb2], q0p);
            e1p = fma2(wea, xv1[ca], e1p); e1p = fma2(web, xv1[cb2], e1p);
            q1p = fma2(woa, xv1[ca], q1p); q1p = fma2(wob, xv1[cb2], q1p);
        }
        const float e0 = we[34] + e0p.x + e0p.y;          // + b1[h]
        const float q0 = wo[34] + q0p.x + q0p.y;
        const float e1 = we[34] + e1p.x + e1p.y;
        const float q1 = wo[34] + q1p.x + q1p.y;
        // bank = (cell*33 + k)%32 = (cell + k)%32 across lanes: conflict-free
        row0[j] = (unsigned int)f2bf(e0) | ((unsigned int)f2bf(q0) << 16);
        row1[j] = (unsigned int)f2bf(e1) | ((unsigned int)f2bf(q1) << 16);
    }
    __syncthreads();

    // Copy-out: already bf16-packed; linear coalesced uint4 stores.
    uint4* ob4 = (uint4*)(hxb + ((size_t)b * G_ + tile) * H_);
#pragma unroll
    for (int k = 0; k < 4; ++k) {
        const int L4 = t + k * 256;            // uint4 index (8 bf16)
        const int cell = L4 >> 3;
        const int base = (L4 & 7) * 4;         // uint offset within cell
        const unsigned int* s = s_hx + cell * RS + base;
        ob4[L4] = make_uint4(s[0], s[1], s[2], s[3]);
    }
}

// ---------------------------------------------------------------------------
// Kernel B: one thread per (b, n) point.  (unchanged from R16)
//   idx = idxarr[b][n] & (G-1)   (poison-safe, 1 op)
//   Layer 1 scalar fmaf; ReLU + layer 2 packed (v_pk_max/v_pk_fma).
//   W1/W2/b2 stay uniform-address global loads (R9: don't use LDS pipe).
// ---------------------------------------------------------------------------
__global__ __launch_bounds__(256) void point_kernel(
    const unsigned short* __restrict__ hxb, const float* __restrict__ b_rnd,
    const float* __restrict__ W1, const float* __restrict__ W2,
    const float* __restrict__ b2, const int* __restrict__ idxarr,
    float* __restrict__ out0, float* __restrict__ reg_out) {
    const int b = blockIdx.y;
    const int n = blockIdx.x * 256 + threadIdx.x;

    const int idx = idxarr[(size_t)b * N_ + n] & (G_ - 1);   // poison-safe
    const float r0 = b_rnd[((size_t)b * 2 + 0) * N_ + n];
    const float r1 = b_rnd[((size_t)b * 2 + 1) * N_ + n];
    const unsigned short* hp = hxb + ((size_t)b * G_ + idx) * H_;

    v2f o0p = {0.f, 0.f}, o1p = {0.f, 0.f}, o2p = {0.f, 0.f};
    const v2f zz = {0.f, 0.f};
#pragma unroll
    for (int g = 0; g < 8; ++g) {              // 8 h per group, one uint4
        const uint4 u = *(const uint4*)(hp + g * 8);
        const unsigned int uw[4] = {u.x, u.y, u.z, u.w};
#pragma unroll
        for (int q = 0; q < 4; ++q) {
            const int h = g * 8 + 2 * q;       // even h of the pair
            union { unsigned int u; float f; } a, bwd;
            a.u = uw[q] << 16;                 // even h
            bwd.u = uw[q] & 0xFFFF0000u;       // odd h
            // Layer 1: scalar (non-contiguous W1 pairs)
            float he = a.f, ho = bwd.f;
            he = fmaf(W1[h * 34 + 32], r0, he);
            he = fmaf(W1[h * 34 + 33], r1, he);
            ho = fmaf(W1[(h + 1) * 34 + 32], r0, ho);
            ho = fmaf(W1[(h + 1) * 34 + 33], r1, ho);
            // ReLU + layer 2: packed
            v2f hv2; hv2.x = he; hv2.y = ho;
            hv2 = __builtin_elementwise_max(hv2, zz);
            o0p = fma2(*(const v2f*)(W2 + 0 * H_ + h), hv2, o0p);
            o1p = fma2(*(const v2f*)(W2 + 1 * H_ + h), hv2, o1p);
            o2p = fma2(*(const v2f*)(W2 + 2 * H_ + h), hv2, o2p);
        }
    }
    float o0 = b2[0] + o0p.x + o0p.y;
    float o1 = b2[1] + o1p.x + o1p.y;
    float o2 = b2[2] + o2p.x + o2p.y;

    const float nrm = sqrtf(o0 * o0 + o1 * o1 + o2 * o2);
    const float reg = fmaxf(nrm - REG_THR, 0.0f);

    // grid_o[k][idx] = (i_k + 0.5)/16 - 0.5, exact in fp32 from idx bits.
    o0 += (float)((idx >> 8) & 15) * 0.0625f - 0.46875f;
    o1 += (float)((idx >> 4) & 15) * 0.0625f - 0.46875f;
    o2 += (float)(idx & 15) * 0.0625f - 0.46875f;

    float* p = out0 + ((size_t)b * 3) * N_ + n;
    p[0]              = o0;
    p[N_]             = o1;
    p[2 * (size_t)N_] = o2;
    reg_out[(size_t)b * N_ + n] = reg;
}

// ---------------------------------------------------------------------------
extern "C" void kernel_launch(void* const* d_in, const int* in_sizes, int n_in,
                              void* d_out, int out_size, void* d_ws, size_t ws_size,
                              hipStream_t stream) {
    const float* x      = (const float*)d_in[0];  // (B, C, RES, RES, RES)
    const int*   counts = (const int*)  d_in[1];  // (B, G)
    const float* b_rnd  = (const float*)d_in[2];  // (B, 2, N)
    // d_in[3] = grid_o: unused (recomputed exactly from idx bits)
    const float* W1     = (const float*)d_in[4];  // (H, C+2)
    const float* b1     = (const float*)d_in[5];  // (H,)
    const float* W2     = (const float*)d_in[6];  // (3, H)
    const float* b2     = (const float*)d_in[7];  // (3,)

    float* out  = (float*)d_out;                  // (B, 3, N) then (B, N)
    float* rout = out + (size_t)B_ * 3 * N_;

    int* idxarr = (int*)d_ws;                     // B*N ints = 2 MB
    unsigned short* hxb =
        (unsigned short*)((char*)d_ws + (size_t)B_ * N_ * sizeof(int));
                                                  // B*G*H bf16 = 16.8 MB

    dim3 gridA(G_ / TCELL + 1, B_);               // (33, 32): +1 col = scan
    dim3 gridB(N_ / 256, B_);

    hx_scan_kernel<<<gridA, 256, 0, stream>>>(x, W1, b1, counts, hxb, idxarr);
    point_kernel<<<gridB, 256, 0, stream>>>(hxb, b_rnd, W1, W2, b2,
                                            idxarr, out, rout);
}